// Round 4
// baseline (202.350 us; speedup 1.0000x reference)
//
#include <hip/hip_runtime.h>
#include <math.h>

typedef __attribute__((ext_vector_type(8))) __bf16 bf16x8;
typedef __attribute__((ext_vector_type(4))) __bf16 bf16x4;
typedef __attribute__((ext_vector_type(4))) float f32x4;

constexpr int kBATCH = 2;
constexpr int kS = 2048;
constexpr int kE = 1024;
constexpr int kH = 16;
constexpr int kD = 64;
constexpr float kScale = 0.125f;                    // D^-0.5
// exp2 trick: fold log2(e) into the Q pre-scale so attn uses raw v_exp_f32
// (exp2) with no per-element multiply. softmax is invariant to the base swap.
constexpr float kQScale = 0.125f * 1.44269504088896340736f;

// async global->LDS, 16B per lane. LDS dest is wave-uniform base + lane*16.
__device__ inline void gl2lds16(const void* g, void* l) {
    __builtin_amdgcn_global_load_lds((const __attribute__((address_space(1))) void*)g,
                                     (__attribute__((address_space(3))) void*)l, 16, 0, 0);
}

// ---------------------------------------------------------------------------
// fp32 -> bf16 convert, two buffers in one launch (range select), PLUS
// rope cos/sin table generation (blocks >= 7168): tab[s*32+i] = {cos,sin}
// of s * 10000^(-i/32). On-device trig once here instead of 2M times in rope.
// ---------------------------------------------------------------------------
__global__ __launch_bounds__(256) void cvt2_kernel(const float* __restrict__ a, __bf16* __restrict__ oa, int na,
                                                   const float* __restrict__ b, __bf16* __restrict__ ob,
                                                   float2* __restrict__ tab) {
    if (blockIdx.x >= 7168) {
        int e = (blockIdx.x - 7168) * 1024 + threadIdx.x * 4;
#pragma unroll
        for (int j = 0; j < 4; ++j) {
            int ee = e + j;
            int s = ee >> 5, i = ee & 31;
            float inv = expf(-(float)i * (9.210340371976184f / 32.0f));  // 10000^(-i/32)
            float ang = (float)s * inv;
            tab[ee] = make_float2(cosf(ang), sinf(ang));
        }
        return;
    }
    int idx = (blockIdx.x * 256 + threadIdx.x) * 4;
    const float* src;
    __bf16* dst;
    if (idx < na) { src = a + idx; dst = oa + idx; }
    else          { src = b + (idx - na); dst = ob + (idx - na); }
    float4 f = *(const float4*)src;
    bf16x4 r;
    r[0] = (__bf16)f.x; r[1] = (__bf16)f.y; r[2] = (__bf16)f.z; r[3] = (__bf16)f.w;
    *(bf16x4*)dst = r;
}

// ---------------------------------------------------------------------------
// QKV projection GEMM with FUSED RoPE epilogue.
// C[m,n] = sum_k A[m,k] * W[n,k]; 128x128 tile, BK=64, gl2lds + XOR swizzle.
// Epilogue: each wave-half's 64 cols are exactly one head of one of q/k/v
// (boundaries at 1024/2048 are multiples of 64). For q/k, rope pairs
// (2i,2i+1) live in adjacent lanes -> __shfl_xor(v,1) gives the partner;
// cos/sin from tab (fp32). q pre-scaled by kQScale. Outputs go directly to
// head-major qd/kd [bh][s][64]; v goes compactly to vraw [b*S+s][1024].
// This removes the standalone rope pass (16MB read + 16MB write + 2M-thread
// trig) entirely.
// ---------------------------------------------------------------------------
__global__ __launch_bounds__(256) void gemm_qkv_kernel(const __bf16* __restrict__ A,
                                                       const __bf16* __restrict__ W,
                                                       __bf16* __restrict__ vraw,
                                                       __bf16* __restrict__ qd,
                                                       __bf16* __restrict__ kd,
                                                       const float2* __restrict__ tab) {
    constexpr int kK = 1024;
    __shared__ __bf16 As[128 * 64] __attribute__((aligned(16)));
    __shared__ __bf16 Bs[128 * 64] __attribute__((aligned(16)));

    const int tid  = threadIdx.x;
    const int lane = tid & 63;
    const int quad = lane >> 4;
    const int l16  = lane & 15;
    const int rx   = l16 & 7;
    const int wave = tid >> 6;
    const int wm   = (wave >> 1) * 64;
    const int wn   = (wave & 1) * 64;
    const int m0   = blockIdx.y * 128;
    const int n0   = blockIdx.x * 128;

    const int srow8  = lane >> 3;                  // 0..7
    const int schunk = ((lane & 7) ^ srow8) * 8;   // swizzled source col (elems)

    f32x4 zero = {0.f, 0.f, 0.f, 0.f};
    f32x4 acc[4][4];
#pragma unroll
    for (int i = 0; i < 4; ++i)
#pragma unroll
        for (int j = 0; j < 4; ++j) acc[i][j] = zero;

    for (int kt = 0; kt < kK; kt += 64) {
        __syncthreads();   // previous tile's readers done
#pragma unroll
        for (int i = 0; i < 4; ++i) {
            int rbase = wave * 32 + i * 8;
            gl2lds16(A + (size_t)(m0 + rbase + srow8) * kK + kt + schunk, &As[rbase * 64]);
            gl2lds16(W + (size_t)(n0 + rbase + srow8) * kK + kt + schunk, &Bs[rbase * 64]);
        }
        __syncthreads();   // loads landed

#pragma unroll
        for (int kk = 0; kk < 2; ++kk) {
            bf16x8 af[4], bf[4];
#pragma unroll
            for (int mi = 0; mi < 4; ++mi)
                af[mi] = *(const bf16x8*)(&As[(wm + mi * 16 + l16) * 64 + (((kk * 4 + quad) ^ rx)) * 8]);
#pragma unroll
            for (int ni = 0; ni < 4; ++ni)
                bf[ni] = *(const bf16x8*)(&Bs[(wn + ni * 16 + l16) * 64 + (((kk * 4 + quad) ^ rx)) * 8]);
#pragma unroll
            for (int mi = 0; mi < 4; ++mi)
#pragma unroll
                for (int ni = 0; ni < 4; ++ni)
                    acc[mi][ni] = __builtin_amdgcn_mfma_f32_16x16x32_bf16(af[mi], bf[ni], acc[mi][ni], 0, 0, 0);
        }
    }

    // -------- fused epilogue --------
    const int col0 = n0 + wn;            // multiple of 64; whole wave one region
    const int reg  = col0 >> 10;         // 0=q, 1=k, 2=v
    const int h    = (col0 >> 6) & 15;

    if (reg == 2) {
#pragma unroll
        for (int mi = 0; mi < 4; ++mi)
#pragma unroll
            for (int ni = 0; ni < 4; ++ni)
#pragma unroll
                for (int r = 0; r < 4; ++r) {
                    int row  = m0 + wm + mi * 16 + quad * 4 + r;
                    int colv = col0 - 2048 + ni * 16 + l16;
                    vraw[(size_t)row * kE + colv] = (__bf16)acc[mi][ni][r];
                }
    } else {
        __bf16* dst = reg ? kd : qd;
        const float qs = reg ? 1.0f : kQScale;
        const bool odd = (l16 & 1);
#pragma unroll
        for (int mi = 0; mi < 4; ++mi)
#pragma unroll
            for (int r = 0; r < 4; ++r) {
                int srow = m0 + wm + mi * 16 + quad * 4 + r;
                int sloc = srow & (kS - 1);
                int bb   = srow >> 11;
                const float2* trow = tab + sloc * 32;
                __bf16* drow = dst + ((size_t)(bb * kH + h) * kS + sloc) * kD;
#pragma unroll
                for (int ni = 0; ni < 4; ++ni) {
                    int d = ni * 16 + l16;
                    float2 cs = trow[d >> 1];
                    float v  = acc[mi][ni][r];
                    float pv = __shfl_xor(v, 1);
                    // even lane: xr=v, xi=pv -> out_r = xr*c - xi*s
                    // odd lane:  xr=pv, xi=v -> out_i = xr*s + xi*c
                    float out = odd ? (pv * cs.y + v * cs.x) : (v * cs.x - pv * cs.y);
                    drow[d] = (__bf16)(qs * out);
                }
            }
    }
}

// ---------------------------------------------------------------------------
// Generic GEMM (used for the output projection): C = A * W^T, fp32 out.
// ---------------------------------------------------------------------------
template <int TN, typename TC>
__global__ __launch_bounds__(256) void gemm_bt_kernel(const __bf16* __restrict__ A,
                                                      const __bf16* __restrict__ W,
                                                      TC* __restrict__ C,
                                                      int M, int N, int K) {
    constexpr int NI = TN / 32;        // n-frags per wave
    __shared__ __bf16 As[128 * 64] __attribute__((aligned(16)));
    __shared__ __bf16 Bs[TN * 64] __attribute__((aligned(16)));

    const int tid  = threadIdx.x;
    const int lane = tid & 63;
    const int quad = lane >> 4;
    const int l16  = lane & 15;
    const int rx   = l16 & 7;
    const int wave = tid >> 6;
    const int wm   = (wave >> 1) * 64;
    const int wn   = (wave & 1) * (TN / 2);
    const int m0   = blockIdx.y * 128;
    const int n0   = blockIdx.x * TN;

    const int srow8  = lane >> 3;                  // 0..7
    const int schunk = ((lane & 7) ^ srow8) * 8;   // swizzled source col (elems)

    f32x4 zero = {0.f, 0.f, 0.f, 0.f};
    f32x4 acc[4][NI];
#pragma unroll
    for (int i = 0; i < 4; ++i)
#pragma unroll
        for (int j = 0; j < NI; ++j) acc[i][j] = zero;

    for (int kt = 0; kt < K; kt += 64) {
        __syncthreads();   // previous tile's readers done
#pragma unroll
        for (int i = 0; i < 4; ++i) {
            int rbase = wave * 32 + i * 8;
            gl2lds16(A + (size_t)(m0 + rbase + srow8) * K + kt + schunk, &As[rbase * 64]);
        }
#pragma unroll
        for (int i = 0; i < NI; ++i) {
            int rbase = wave * (TN / 4) + i * 8;
            gl2lds16(W + (size_t)(n0 + rbase + srow8) * K + kt + schunk, &Bs[rbase * 64]);
        }
        __syncthreads();   // loads landed

#pragma unroll
        for (int kk = 0; kk < 2; ++kk) {
            bf16x8 af[4], bf[NI];
#pragma unroll
            for (int mi = 0; mi < 4; ++mi)
                af[mi] = *(const bf16x8*)(&As[(wm + mi * 16 + l16) * 64 + (((kk * 4 + quad) ^ rx)) * 8]);
#pragma unroll
            for (int ni = 0; ni < NI; ++ni)
                bf[ni] = *(const bf16x8*)(&Bs[(wn + ni * 16 + l16) * 64 + (((kk * 4 + quad) ^ rx)) * 8]);
#pragma unroll
            for (int mi = 0; mi < 4; ++mi)
#pragma unroll
                for (int ni = 0; ni < NI; ++ni)
                    acc[mi][ni] = __builtin_amdgcn_mfma_f32_16x16x32_bf16(af[mi], bf[ni], acc[mi][ni], 0, 0, 0);
        }
    }

#pragma unroll
    for (int mi = 0; mi < 4; ++mi)
#pragma unroll
        for (int ni = 0; ni < NI; ++ni)
#pragma unroll
            for (int r = 0; r < 4; ++r) {
                int row = m0 + wm + mi * 16 + quad * 4 + r;
                int col = n0 + wn + ni * 16 + l16;
                C[(size_t)row * N + col] = (TC)acc[mi][ni][r];
            }
}

// ---------------------------------------------------------------------------
// Sigma-permuted V-transpose (vt position p within each 32-key group holds
// source key sigma(p) = ((p&7)>>2)*16 + ((p>>3)&3)*4 + (p&3)), so attn can
// feed exp'd S^T registers directly as the PV A-fragment. Reads compact vraw.
// ---------------------------------------------------------------------------
__global__ __launch_bounds__(256) void vtrans_kernel(const __bf16* __restrict__ vraw,
                                                     __bf16* __restrict__ vt) {
    __shared__ __bf16 tile[64 * 72] __attribute__((aligned(16)));

    int flat = blockIdx.x;                 // 0..1023
    int s0 = (flat & 31) * 64;
    int bh = flat >> 5;
    int b = bh >> 4, h = bh & 15;
    int tid = threadIdx.x;

#pragma unroll
    for (int p = 0; p < 2; ++p) {
        int c = tid + p * 256;           // 0..511
        int r = c >> 3, jc = c & 7;
        *(bf16x8*)&tile[r * 72 + jc * 8] =
            *(const bf16x8*)(vraw + (size_t)(b * kS + s0 + r) * kE + h * kD + jc * 8);
    }
    __syncthreads();
#pragma unroll
    for (int p = 0; p < 2; ++p) {
        int c = tid + p * 256;
        int d = c >> 3, jt = c & 7;      // output chunk jt: positions jt*8+u
        bf16x8 v;
#pragma unroll
        for (int u = 0; u < 8; ++u) {
            int src = (jt >> 2) * 32 + ((u >> 2) << 4) + ((jt & 3) << 2) + (u & 3);
            v[u] = tile[src * 72 + d];
        }
        *(bf16x8*)(vt + (size_t)(bh * kD + d) * kS + s0 + jt * 8) = v;
    }
}

// ---------------------------------------------------------------------------
// Attention, flash-style, no-max softmax (|logit| small; exp2 domain).
// 1-deep softmax pipeline: each iteration computes exp(t-1) || QK(t) ||
// sum+PV(t-1) in one basic block; sg ping-pongs in registers across the
// barrier; K ring-2 + V ring-4 in LDS (48KB/block, 2 blocks/CU).
// ---------------------------------------------------------------------------
__global__ __launch_bounds__(256, 2) void attn_kernel(const __bf16* __restrict__ qd,
                                                      const __bf16* __restrict__ kd,
                                                      const __bf16* __restrict__ vt,
                                                      __bf16* __restrict__ ctx,
                                                      const float* __restrict__ wout,
                                                      __bf16* __restrict__ woutb) {
    __shared__ __bf16 Ks[2][64 * 64] __attribute__((aligned(16)));
    __shared__ __bf16 Vs[4][64 * 64] __attribute__((aligned(16)));

    const int lane = threadIdx.x & 63;
    const int wave = threadIdx.x >> 6;   // 0..3
    const int quad = lane >> 4;
    const int l16  = lane & 15;
    const int rx   = l16 & 7;

    // folded w_out convert: 2048 elems per block (512 blocks), 8 per thread
    {
        int base = blockIdx.x * 2048 + threadIdx.x * 8;
#pragma unroll
        for (int p = 0; p < 2; ++p) {
            float4 f = *(const float4*)(wout + base + p * 4);
            bf16x4 r;
            r[0] = (__bf16)f.x; r[1] = (__bf16)f.y; r[2] = (__bf16)f.z; r[3] = (__bf16)f.w;
            *(bf16x4*)(woutb + base + p * 4) = r;
        }
    }

    // XCD-aware decode: flat%8 = XCD; each XCD owns heads 4x..4x+3.
    // 512 blocks, 16 blocks per bh, 128 q-rows per block.
    const int flat = blockIdx.x;                  // 0..511
    const int s    = flat >> 3;                   // 0..63
    const int bh   = (flat & 7) * 4 + (s >> 4);   // 0..31
    const int q0   = (s & 15) * 128;
    const int b  = bh >> 4;
    const int h  = bh & 15;

    const __bf16* qp = qd + (size_t)bh * kS * kD;
    const __bf16* kp = kd + (size_t)bh * kS * kD;
    const __bf16* vp = vt + (size_t)bh * kD * kS;

    const int srow8  = lane >> 3;
    const int schunk = ((lane & 7) ^ srow8) * 8;

    // q fragments (pre-scaled by kQScale): B-operand of S^T = K*Q^T.
    // Two q-groups of 16 rows each -> every K/V LDS read feeds 2 MFMA.
    bf16x8 aq[2][2];
#pragma unroll
    for (int qg = 0; qg < 2; ++qg) {
        const __bf16* qrow = qp + (size_t)(q0 + wave * 32 + qg * 16 + l16) * kD + quad * 8;
        aq[qg][0] = *(const bf16x8*)(qrow);
        aq[qg][1] = *(const bf16x8*)(qrow + 32);
    }

    bf16x8 vone;
#pragma unroll
    for (int u = 0; u < 8; ++u) vone[u] = (__bf16)1.0f;

    f32x4 zero = {0.f, 0.f, 0.f, 0.f};
    f32x4 acc[2][4];
    f32x4 asum[2] = {zero, zero};
#pragma unroll
    for (int qg = 0; qg < 2; ++qg)
#pragma unroll
        for (int i = 0; i < 4; ++i) acc[qg][i] = zero;

    // sg ping-pong: sgb[t&1] written by QK(t), read by exp in body(t+1).
    f32x4 sgb[2][2][4];

    // hoisted LDS read offsets (elements; compile-time indexed -> registers)
    int koff[4][2], voff[4][2];
#pragma unroll
    for (int g = 0; g < 4; ++g) {
        int row = g * 16 + l16;
        koff[g][0] = row * 64 + ((quad       ^ rx)) * 8;
        koff[g][1] = row * 64 + (((quad + 4) ^ rx)) * 8;
        voff[g][0] = row * 64 + ((quad       ^ (row & 7))) * 8;
        voff[g][1] = row * 64 + (((quad + 4) ^ (row & 7))) * 8;
    }

    // staging pointers, bumped per tile (no per-iter 64-bit remultiply)
    const __bf16* kst[2];
    const __bf16* vst[2];
#pragma unroll
    for (int c = 0; c < 2; ++c) {
        int i = wave * 2 + c;
        kst[c] = kp + (size_t)(i * 8 + srow8) * kD + schunk;
        vst[c] = vp + (size_t)(i * 8 + srow8) * kS + schunk;
    }

    auto stage = [&](int ks, int vs) __attribute__((always_inline)) -> void {
#pragma unroll
        for (int c = 0; c < 2; ++c) {
            gl2lds16(kst[c], &Ks[ks][(wave * 2 + c) * 512]);
            gl2lds16(vst[c], &Vs[vs][(wave * 2 + c) * 512]);
            kst[c] += 64 * kD;
            vst[c] += 64;
        }
    };

    // QK^T for tile in Ks[kbuf] -> sgb[par]: 8 reads, 16 MFMA
    auto qk = [&](int kbuf, int par) __attribute__((always_inline)) -> void {
#pragma unroll
        for (int g = 0; g < 4; ++g) {
            bf16x8 a0 = *(const bf16x8*)&Ks[kbuf][koff[g][0]];
            bf16x8 a1 = *(const bf16x8*)&Ks[kbuf][koff[g][1]];
#pragma unroll
            for (int qg = 0; qg < 2; ++qg) {
                f32x4 t = __builtin_amdgcn_mfma_f32_16x16x32_bf16(a0, aq[qg][0], zero, 0, 0, 0);
                sgb[par][qg][g] = __builtin_amdgcn_mfma_f32_16x16x32_bf16(a1, aq[qg][1], t, 0, 0, 0);
            }
        }
    };

    // exp2(sgb[par]) -> PV A-fragments (sigma-matched to vt layout)
    auto expand = [&](bf16x8 (&ap)[2][2], int par) __attribute__((always_inline)) -> void {
#pragma unroll
        for (int qg = 0; qg < 2; ++qg)
#pragma unroll
            for (int r = 0; r < 4; ++r) {
                ap[qg][0][r]     = (__bf16)__builtin_amdgcn_exp2f(sgb[par][qg][0][r]);
                ap[qg][0][4 + r] = (__bf16)__builtin_amdgcn_exp2f(sgb[par][qg][1][r]);
                ap[qg][1][r]     = (__bf16)__builtin_amdgcn_exp2f(sgb[par][qg][2][r]);
                ap[qg][1][4 + r] = (__bf16)__builtin_amdgcn_exp2f(sgb[par][qg][3][r]);
            }
    };

    // sum + PV for tile in Vs[vbuf]: 8 reads, 20 MFMA
    auto sumpv = [&](int vbuf, bf16x8 (&ap)[2][2]) __attribute__((always_inline)) -> void {
#pragma unroll
        for (int qg = 0; qg < 2; ++qg) {
            asum[qg] = __builtin_amdgcn_mfma_f32_16x16x32_bf16(ap[qg][0], vone, asum[qg], 0, 0, 0);
            asum[qg] = __builtin_amdgcn_mfma_f32_16x16x32_bf16(ap[qg][1], vone, asum[qg], 0, 0, 0);
        }
#pragma unroll
        for (int nt = 0; nt < 4; ++nt) {
            bf16x8 bv0 = *(const bf16x8*)&Vs[vbuf][voff[nt][0]];
            bf16x8 bv1 = *(const bf16x8*)&Vs[vbuf][voff[nt][1]];
#pragma unroll
            for (int qg = 0; qg < 2; ++qg) {
                acc[qg][nt] = __builtin_amdgcn_mfma_f32_16x16x32_bf16(ap[qg][0], bv0, acc[qg][nt], 0, 0, 0);
                acc[qg][nt] = __builtin_amdgcn_mfma_f32_16x16x32_bf16(ap[qg][1], bv1, acc[qg][nt], 0, 0, 0);
            }
        }
    };

    // body(t): barrier (tile t resident); stage t+1; exp(t-1) || QK(t) ||
    // sum+PV(t-1). pin = (t-1)&1; kbuf = t&1; vprev = (t-1)&3; vnext = (t+1)&3.
    auto body = [&](int kbuf, int vprev, int vnext, bool pf, int pin)
        __attribute__((always_inline)) -> void {
        __syncthreads();
        if (pf) stage(kbuf ^ 1, vnext);
        bf16x8 ap[2][2];
        expand(ap, pin);
        __builtin_amdgcn_s_setprio(1);
        qk(kbuf, pin ^ 1);
        sumpv(vprev, ap);
        __builtin_amdgcn_s_setprio(0);
    };

    // prologue: stage tile 0; peel t=0 (QK only)
    stage(0, 0);
    __syncthreads();             // tile 0 resident
    stage(1, 1);                 // tile 1 in flight during QK(0)
    __builtin_amdgcn_s_setprio(1);
    qk(0, 0);
    __builtin_amdgcn_s_setprio(0);

    // steady state: t = 1..28 (7 macro-iters x 4, all slots compile-time)
#pragma unroll 1
    for (int t0 = 1; t0 < 29; t0 += 4) {
        body(1, 0, 2, true, 0);   // t = t0+0 (odd)
        body(0, 1, 3, true, 1);   // t = t0+1
        body(1, 2, 0, true, 0);   // t = t0+2
        body(0, 3, 1, true, 1);   // t = t0+3
    }
    // tail: t = 29, 30, 31
    body(1, 0, 2, true, 0);      // t=29
    body(0, 1, 3, true, 1);      // t=30
    body(1, 2, 0, false, 0);     // t=31 (no stage left)

    // epilogue: finish tile 31 (sg in sgb[1], V in Vs[3])
    {
        bf16x8 ap[2][2];
        expand(ap, 1);
        sumpv(3, ap);
    }

#pragma unroll
    for (int qg = 0; qg < 2; ++qg)
#pragma unroll
        for (int r = 0; r < 4; ++r) {
            float inv_l = 1.0f / asum[qg][r];
            int srow_q = q0 + wave * 32 + qg * 16 + quad * 4 + r;
#pragma unroll
            for (int nt = 0; nt < 4; ++nt) {
                int col = h * kD + nt * 16 + l16;
                ctx[(size_t)(b * kS + srow_q) * kE + col] = (__bf16)(acc[qg][nt][r] * inv_l);
            }
        }
}

// ---------------------------------------------------------------------------
extern "C" void kernel_launch(void* const* d_in, const int* in_sizes, int n_in,
                              void* d_out, int out_size, void* d_ws, size_t ws_size,
                              hipStream_t stream) {
    const float* query = (const float*)d_in[0];
    // d_in[1] (key) and d_in[2] (value) are unused by the reference
    const float* w_qkv = (const float*)d_in[3];
    const float* w_out = (const float*)d_in[4];
    float* out = (float*)d_out;

    const int M = kBATCH * kS;             // 4096
    const int nQ = M * kE;                 // 4,194,304
    const int nWqkv = 3 * kE * kE;         // 3,145,728

    // workspace (<48 MB, lifetime-overlapped):
    //   [0,8M)    query_b (GEMM1 A)      -> later ctx (attn out)
    //   [8,14M)   w_qkv_b (GEMM1 W)      -> later w_out_b [8,10M)
    //   [14,14.5M) rope cos/sin table (fp32, 2048x32 float2)
    //   [16,24M)  vraw (GEMM1 V output, compact [b*S+s][1024])
    //   [24,32M)  qd   [32,40M) kd   [40,48M) vt
    char* ws = (char*)d_ws;
    __bf16* query_b = (__bf16*)ws;
    __bf16* w_qkv_b = (__bf16*)(ws + ((size_t)8 << 20));
    float2* tab     = (float2*)(ws + ((size_t)14 << 20));
    __bf16* vraw    = (__bf16*)(ws + ((size_t)16 << 20));
    __bf16* qd      = (__bf16*)(ws + ((size_t)24 << 20));
    __bf16* kd      = (__bf16*)(ws + ((size_t)32 << 20));
    __bf16* vt      = (__bf16*)(ws + ((size_t)40 << 20));
    __bf16* ctx     = (__bf16*)ws;                       // alias, post-GEMM1
    __bf16* w_out_b = (__bf16*)(ws + ((size_t)8 << 20)); // alias, post-GEMM1

    // 1) fp32 -> bf16 for query + w_qkv, plus rope trig table (64 blocks)
    cvt2_kernel<<<7168 + 64, 256, 0, stream>>>(query, query_b, nQ, w_qkv, w_qkv_b, tab);

    // 2) QKV projection with fused RoPE epilogue (q pre-scaled) + compact V
    gemm_qkv_kernel<<<dim3(3 * kE / 128, M / 128), 256, 0, stream>>>(
        query_b, w_qkv_b, vraw, qd, kd, tab);

    // 3) sigma-permuted V transpose (reads compact vraw)
    vtrans_kernel<<<1024, 256, 0, stream>>>(vraw, vt);

    // 4) attention (4 waves x 32 q-rows, 1-deep softmax pipeline, K2/V4 rings)
    attn_kernel<<<512, 256, 0, stream>>>(qd, kd, vt, ctx, w_out, w_out_b);

    // 5) output projection (128x64 tile -> 512 blocks, fp32 out)
    gemm_bt_kernel<64, float>
        <<<dim3(kE / 64, M / 128), 256, 0, stream>>>(ctx, w_out_b, out, M, kE, kE);
}

// Round 6
// 195.557 us; speedup vs baseline: 1.0347x; 1.0347x over previous
//
#include <hip/hip_runtime.h>
#include <math.h>

typedef __attribute__((ext_vector_type(8))) __bf16 bf16x8;
typedef __attribute__((ext_vector_type(4))) __bf16 bf16x4;
typedef __attribute__((ext_vector_type(4))) float f32x4;

constexpr int kBATCH = 2;
constexpr int kS = 2048;
constexpr int kE = 1024;
constexpr int kH = 16;
constexpr int kD = 64;
constexpr float kScale = 0.125f;                    // D^-0.5
// exp2 trick: fold log2(e) into the Q pre-scale so attn uses raw v_exp_f32
// (exp2) with no per-element multiply. softmax is invariant to the base swap.
constexpr float kQScale = 0.125f * 1.44269504088896340736f;

// async global->LDS, 16B per lane. LDS dest is wave-uniform base + lane*16.
__device__ inline void gl2lds16(const void* g, void* l) {
    __builtin_amdgcn_global_load_lds((const __attribute__((address_space(1))) void*)g,
                                     (__attribute__((address_space(3))) void*)l, 16, 0, 0);
}

// ---------------------------------------------------------------------------
// fp32 -> bf16 convert, two buffers in one launch (range select), PLUS
// rope cos/sin table generation (blocks >= 7168): tab[s*32+i] = {cos,sin}
// of s * 10000^(-i/32). Trig computed once here (65536 entries) instead of
// 2M times in the rope pass.
// ---------------------------------------------------------------------------
__global__ __launch_bounds__(256) void cvt2_kernel(const float* __restrict__ a, __bf16* __restrict__ oa, int na,
                                                   const float* __restrict__ b, __bf16* __restrict__ ob,
                                                   float2* __restrict__ tab) {
    if (blockIdx.x >= 7168) {
        int e = (blockIdx.x - 7168) * 1024 + threadIdx.x * 4;
#pragma unroll
        for (int j = 0; j < 4; ++j) {
            int ee = e + j;
            int s = ee >> 5, i = ee & 31;
            float inv = expf(-(float)i * (9.210340371976184f / 32.0f));  // 10000^(-i/32)
            float ang = (float)s * inv;
            tab[ee] = make_float2(cosf(ang), sinf(ang));
        }
        return;
    }
    int idx = (blockIdx.x * 256 + threadIdx.x) * 4;
    const float* src;
    __bf16* dst;
    if (idx < na) { src = a + idx; dst = oa + idx; }
    else          { src = b + (idx - na); dst = ob + (idx - na); }
    float4 f = *(const float4*)src;
    bf16x4 r;
    r[0] = (__bf16)f.x; r[1] = (__bf16)f.y; r[2] = (__bf16)f.z; r[3] = (__bf16)f.w;
    *(bf16x4*)dst = r;
}

// ---------------------------------------------------------------------------
// GEMM: C[m,n] = sum_k A[m,k] * W[n,k], bf16 in. Tile 128 x TN, BK=64,
// global_load_lds staging with XOR-chunk swizzle (conflict-free frag reads).
// ---------------------------------------------------------------------------
template <int TN, typename TC>
__global__ __launch_bounds__(256) void gemm_bt_kernel(const __bf16* __restrict__ A,
                                                      const __bf16* __restrict__ W,
                                                      TC* __restrict__ C,
                                                      int M, int N, int K) {
    constexpr int NI = TN / 32;        // n-frags per wave
    __shared__ __bf16 As[128 * 64] __attribute__((aligned(16)));
    __shared__ __bf16 Bs[TN * 64] __attribute__((aligned(16)));

    const int tid  = threadIdx.x;
    const int lane = tid & 63;
    const int quad = lane >> 4;
    const int l16  = lane & 15;
    const int rx   = l16 & 7;
    const int wave = tid >> 6;
    const int wm   = (wave >> 1) * 64;
    const int wn   = (wave & 1) * (TN / 2);
    const int m0   = blockIdx.y * 128;
    const int n0   = blockIdx.x * TN;

    const int srow8  = lane >> 3;                  // 0..7
    const int schunk = ((lane & 7) ^ srow8) * 8;   // swizzled source col (elems)

    f32x4 zero = {0.f, 0.f, 0.f, 0.f};
    f32x4 acc[4][NI];
#pragma unroll
    for (int i = 0; i < 4; ++i)
#pragma unroll
        for (int j = 0; j < NI; ++j) acc[i][j] = zero;

    for (int kt = 0; kt < K; kt += 64) {
        __syncthreads();   // previous tile's readers done
#pragma unroll
        for (int i = 0; i < 4; ++i) {
            int rbase = wave * 32 + i * 8;
            gl2lds16(A + (size_t)(m0 + rbase + srow8) * K + kt + schunk, &As[rbase * 64]);
        }
#pragma unroll
        for (int i = 0; i < NI; ++i) {
            int rbase = wave * (TN / 4) + i * 8;
            gl2lds16(W + (size_t)(n0 + rbase + srow8) * K + kt + schunk, &Bs[rbase * 64]);
        }
        __syncthreads();   // loads landed

#pragma unroll
        for (int kk = 0; kk < 2; ++kk) {
            bf16x8 af[4], bf[NI];
#pragma unroll
            for (int mi = 0; mi < 4; ++mi)
                af[mi] = *(const bf16x8*)(&As[(wm + mi * 16 + l16) * 64 + (((kk * 4 + quad) ^ rx)) * 8]);
#pragma unroll
            for (int ni = 0; ni < NI; ++ni)
                bf[ni] = *(const bf16x8*)(&Bs[(wn + ni * 16 + l16) * 64 + (((kk * 4 + quad) ^ rx)) * 8]);
#pragma unroll
            for (int mi = 0; mi < 4; ++mi)
#pragma unroll
                for (int ni = 0; ni < NI; ++ni)
                    acc[mi][ni] = __builtin_amdgcn_mfma_f32_16x16x32_bf16(af[mi], bf[ni], acc[mi][ni], 0, 0, 0);
        }
    }

#pragma unroll
    for (int mi = 0; mi < 4; ++mi)
#pragma unroll
        for (int ni = 0; ni < NI; ++ni)
#pragma unroll
            for (int r = 0; r < 4; ++r) {
                int row = m0 + wm + mi * 16 + quad * 4 + r;
                int col = n0 + wn + ni * 16 + l16;
                C[(size_t)row * N + col] = (TC)acc[mi][ni][r];
            }
}

// ---------------------------------------------------------------------------
// Merged RoPE (q,k) + sigma-permuted V-transpose.
// Blocks [0,8192): rope (q pre-scaled by kQScale = scale*log2e), cos/sin from
// the precomputed table, packed 4B pair loads/stores;
// [8192,9216): vtrans. vt position p within each 32-key group holds source key
//   sigma(p) = ((p&7)>>2)*16 + ((p>>3)&3)*4 + (p&3)
// so attn can feed exp'd S^T registers directly as the PV A-fragment.
// ---------------------------------------------------------------------------
__global__ __launch_bounds__(256) void rope_vtrans_kernel(const __bf16* __restrict__ qkv,
                                                          __bf16* __restrict__ qd,
                                                          __bf16* __restrict__ kd,
                                                          __bf16* __restrict__ vt,
                                                          const float2* __restrict__ tab) {
    __shared__ __bf16 tile[64 * 72] __attribute__((aligned(16)));

    if (blockIdx.x < 8192) {
        int tid = blockIdx.x * 256 + threadIdx.x;     // 2^21 threads
        int i = tid & 31;
        int h = (tid >> 5) & (kH - 1);
        int s = (tid >> 9) & (kS - 1);
        int b = tid >> 20;

        size_t rowbase = (size_t)(b * kS + s) * (3 * kE);
        int coff = h * kD + 2 * i;

        union { uint u; __bf16 hx[2]; } qa, ka, qo, ko;
        qa.u = *(const uint*)(qkv + rowbase + coff);
        ka.u = *(const uint*)(qkv + rowbase + kE + coff);
        float qr = (float)qa.hx[0];
        float qi = (float)qa.hx[1];
        float kr = (float)ka.hx[0];
        float ki = (float)ka.hx[1];

        float2 cs = tab[s * 32 + i];
        float cv = cs.x;
        float sv = cs.y;

        size_t qbase = ((size_t)(b * kH + h) * kS + s) * kD + 2 * i;
        qo.hx[0] = (__bf16)(kQScale * (qr * cv - qi * sv));
        qo.hx[1] = (__bf16)(kQScale * (qr * sv + qi * cv));
        ko.hx[0] = (__bf16)(kr * cv - ki * sv);
        ko.hx[1] = (__bf16)(kr * sv + ki * cv);
        *(uint*)(qd + qbase) = qo.u;
        *(uint*)(kd + qbase) = ko.u;
    } else {
        int flat = blockIdx.x - 8192;                 // 0..1023
        int s0 = (flat & 31) * 64;
        int bh = flat >> 5;
        int b = bh >> 4, h = bh & 15;
        int tid = threadIdx.x;

#pragma unroll
        for (int p = 0; p < 2; ++p) {
            int c = tid + p * 256;           // 0..511
            int r = c >> 3, jc = c & 7;
            *(bf16x8*)&tile[r * 72 + jc * 8] =
                *(const bf16x8*)(qkv + (size_t)(b * kS + s0 + r) * (3 * kE) + 2 * kE + h * kD + jc * 8);
        }
        __syncthreads();
#pragma unroll
        for (int p = 0; p < 2; ++p) {
            int c = tid + p * 256;
            int d = c >> 3, jt = c & 7;      // output chunk jt: positions jt*8+u
            bf16x8 v;
#pragma unroll
            for (int u = 0; u < 8; ++u) {
                int src = (jt >> 2) * 32 + ((u >> 2) << 4) + ((jt & 3) << 2) + (u & 3);
                v[u] = tile[src * 72 + d];
            }
            *(bf16x8*)(vt + (size_t)(bh * kD + d) * kS + s0 + jt * 8) = v;
        }
    }
}

// ---------------------------------------------------------------------------
// Attention, flash-style, no-max softmax (|logit| small; exp2 domain).
// 1-deep softmax pipeline: each iteration computes exp(t-1) || QK(t) ||
// sum+PV(t-1) in one basic block; sg ping-pongs in registers across the
// barrier; K ring-2 + V ring-4 in LDS (48KB/block, 2 blocks/CU).
// ---------------------------------------------------------------------------
__global__ __launch_bounds__(256, 2) void attn_kernel(const __bf16* __restrict__ qd,
                                                      const __bf16* __restrict__ kd,
                                                      const __bf16* __restrict__ vt,
                                                      __bf16* __restrict__ ctx,
                                                      const float* __restrict__ wout,
                                                      __bf16* __restrict__ woutb) {
    __shared__ __bf16 Ks[2][64 * 64] __attribute__((aligned(16)));
    __shared__ __bf16 Vs[4][64 * 64] __attribute__((aligned(16)));

    const int lane = threadIdx.x & 63;
    const int wave = threadIdx.x >> 6;   // 0..3
    const int quad = lane >> 4;
    const int l16  = lane & 15;
    const int rx   = l16 & 7;

    // folded w_out convert: 2048 elems per block (512 blocks), 8 per thread
    {
        int base = blockIdx.x * 2048 + threadIdx.x * 8;
#pragma unroll
        for (int p = 0; p < 2; ++p) {
            float4 f = *(const float4*)(wout + base + p * 4);
            bf16x4 r;
            r[0] = (__bf16)f.x; r[1] = (__bf16)f.y; r[2] = (__bf16)f.z; r[3] = (__bf16)f.w;
            *(bf16x4*)(woutb + base + p * 4) = r;
        }
    }

    // XCD-aware decode: flat%8 = XCD; each XCD owns heads 4x..4x+3.
    // 512 blocks, 16 blocks per bh, 128 q-rows per block.
    const int flat = blockIdx.x;                  // 0..511
    const int s    = flat >> 3;                   // 0..63
    const int bh   = (flat & 7) * 4 + (s >> 4);   // 0..31
    const int q0   = (s & 15) * 128;
    const int b  = bh >> 4;
    const int h  = bh & 15;

    const __bf16* qp = qd + (size_t)bh * kS * kD;
    const __bf16* kp = kd + (size_t)bh * kS * kD;
    const __bf16* vp = vt + (size_t)bh * kD * kS;

    const int srow8  = lane >> 3;
    const int schunk = ((lane & 7) ^ srow8) * 8;

    // q fragments (pre-scaled by kQScale): B-operand of S^T = K*Q^T.
    // Two q-groups of 16 rows each -> every K/V LDS read feeds 2 MFMA.
    bf16x8 aq[2][2];
#pragma unroll
    for (int qg = 0; qg < 2; ++qg) {
        const __bf16* qrow = qp + (size_t)(q0 + wave * 32 + qg * 16 + l16) * kD + quad * 8;
        aq[qg][0] = *(const bf16x8*)(qrow);
        aq[qg][1] = *(const bf16x8*)(qrow + 32);
    }

    bf16x8 vone;
#pragma unroll
    for (int u = 0; u < 8; ++u) vone[u] = (__bf16)1.0f;

    f32x4 zero = {0.f, 0.f, 0.f, 0.f};
    f32x4 acc[2][4];
    f32x4 asum[2] = {zero, zero};
#pragma unroll
    for (int qg = 0; qg < 2; ++qg)
#pragma unroll
        for (int i = 0; i < 4; ++i) acc[qg][i] = zero;

    // sg ping-pong: sgb[t&1] written by QK(t), read by exp in body(t+1).
    f32x4 sgb[2][2][4];

    // hoisted LDS read offsets (elements; compile-time indexed -> registers)
    int koff[4][2], voff[4][2];
#pragma unroll
    for (int g = 0; g < 4; ++g) {
        int row = g * 16 + l16;
        koff[g][0] = row * 64 + ((quad       ^ rx)) * 8;
        koff[g][1] = row * 64 + (((quad + 4) ^ rx)) * 8;
        voff[g][0] = row * 64 + ((quad       ^ (row & 7))) * 8;
        voff[g][1] = row * 64 + (((quad + 4) ^ (row & 7))) * 8;
    }

    // staging pointers, bumped per tile (no per-iter 64-bit remultiply)
    const __bf16* kst[2];
    const __bf16* vst[2];
#pragma unroll
    for (int c = 0; c < 2; ++c) {
        int i = wave * 2 + c;
        kst[c] = kp + (size_t)(i * 8 + srow8) * kD + schunk;
        vst[c] = vp + (size_t)(i * 8 + srow8) * kS + schunk;
    }

    auto stage = [&](int ks, int vs) __attribute__((always_inline)) -> void {
#pragma unroll
        for (int c = 0; c < 2; ++c) {
            gl2lds16(kst[c], &Ks[ks][(wave * 2 + c) * 512]);
            gl2lds16(vst[c], &Vs[vs][(wave * 2 + c) * 512]);
            kst[c] += 64 * kD;
            vst[c] += 64;
        }
    };

    // QK^T for tile in Ks[kbuf] -> sgb[par]: 8 reads, 16 MFMA
    auto qk = [&](int kbuf, int par) __attribute__((always_inline)) -> void {
#pragma unroll
        for (int g = 0; g < 4; ++g) {
            bf16x8 a0 = *(const bf16x8*)&Ks[kbuf][koff[g][0]];
            bf16x8 a1 = *(const bf16x8*)&Ks[kbuf][koff[g][1]];
#pragma unroll
            for (int qg = 0; qg < 2; ++qg) {
                f32x4 t = __builtin_amdgcn_mfma_f32_16x16x32_bf16(a0, aq[qg][0], zero, 0, 0, 0);
                sgb[par][qg][g] = __builtin_amdgcn_mfma_f32_16x16x32_bf16(a1, aq[qg][1], t, 0, 0, 0);
            }
        }
    };

    // exp2(sgb[par]) -> PV A-fragments (sigma-matched to vt layout)
    auto expand = [&](bf16x8 (&ap)[2][2], int par) __attribute__((always_inline)) -> void {
#pragma unroll
        for (int qg = 0; qg < 2; ++qg)
#pragma unroll
            for (int r = 0; r < 4; ++r) {
                ap[qg][0][r]     = (__bf16)__builtin_amdgcn_exp2f(sgb[par][qg][0][r]);
                ap[qg][0][4 + r] = (__bf16)__builtin_amdgcn_exp2f(sgb[par][qg][1][r]);
                ap[qg][1][r]     = (__bf16)__builtin_amdgcn_exp2f(sgb[par][qg][2][r]);
                ap[qg][1][4 + r] = (__bf16)__builtin_amdgcn_exp2f(sgb[par][qg][3][r]);
            }
    };

    // sum + PV for tile in Vs[vbuf]: 8 reads, 20 MFMA
    auto sumpv = [&](int vbuf, bf16x8 (&ap)[2][2]) __attribute__((always_inline)) -> void {
#pragma unroll
        for (int qg = 0; qg < 2; ++qg) {
            asum[qg] = __builtin_amdgcn_mfma_f32_16x16x32_bf16(ap[qg][0], vone, asum[qg], 0, 0, 0);
            asum[qg] = __builtin_amdgcn_mfma_f32_16x16x32_bf16(ap[qg][1], vone, asum[qg], 0, 0, 0);
        }
#pragma unroll
        for (int nt = 0; nt < 4; ++nt) {
            bf16x8 bv0 = *(const bf16x8*)&Vs[vbuf][voff[nt][0]];
            bf16x8 bv1 = *(const bf16x8*)&Vs[vbuf][voff[nt][1]];
#pragma unroll
            for (int qg = 0; qg < 2; ++qg) {
                acc[qg][nt] = __builtin_amdgcn_mfma_f32_16x16x32_bf16(ap[qg][0], bv0, acc[qg][nt], 0, 0, 0);
                acc[qg][nt] = __builtin_amdgcn_mfma_f32_16x16x32_bf16(ap[qg][1], bv1, acc[qg][nt], 0, 0, 0);
            }
        }
    };

    // body(t): barrier (tile t resident); stage t+1; exp(t-1) || QK(t) ||
    // sum+PV(t-1). pin = (t-1)&1; kbuf = t&1; vprev = (t-1)&3; vnext = (t+1)&3.
    auto body = [&](int kbuf, int vprev, int vnext, bool pf, int pin)
        __attribute__((always_inline)) -> void {
        __syncthreads();
        if (pf) stage(kbuf ^ 1, vnext);
        bf16x8 ap[2][2];
        expand(ap, pin);
        __builtin_amdgcn_s_setprio(1);
        qk(kbuf, pin ^ 1);
        sumpv(vprev, ap);
        __builtin_amdgcn_s_setprio(0);
    };

    // prologue: stage tile 0; peel t=0 (QK only)
    stage(0, 0);
    __syncthreads();             // tile 0 resident
    stage(1, 1);                 // tile 1 in flight during QK(0)
    __builtin_amdgcn_s_setprio(1);
    qk(0, 0);
    __builtin_amdgcn_s_setprio(0);

    // steady state: t = 1..28 (7 macro-iters x 4, all slots compile-time)
#pragma unroll 1
    for (int t0 = 1; t0 < 29; t0 += 4) {
        body(1, 0, 2, true, 0);   // t = t0+0 (odd)
        body(0, 1, 3, true, 1);   // t = t0+1
        body(1, 2, 0, true, 0);   // t = t0+2
        body(0, 3, 1, true, 1);   // t = t0+3
    }
    // tail: t = 29, 30, 31
    body(1, 0, 2, true, 0);      // t=29
    body(0, 1, 3, true, 1);      // t=30
    body(1, 2, 0, false, 0);     // t=31 (no stage left)

    // epilogue: finish tile 31 (sg in sgb[1], V in Vs[3])
    {
        bf16x8 ap[2][2];
        expand(ap, 1);
        sumpv(3, ap);
    }

#pragma unroll
    for (int qg = 0; qg < 2; ++qg)
#pragma unroll
        for (int r = 0; r < 4; ++r) {
            float inv_l = 1.0f / asum[qg][r];
            int srow_q = q0 + wave * 32 + qg * 16 + quad * 4 + r;
#pragma unroll
            for (int nt = 0; nt < 4; ++nt) {
                int col = h * kD + nt * 16 + l16;
                ctx[(size_t)(b * kS + srow_q) * kE + col] = (__bf16)(acc[qg][nt][r] * inv_l);
            }
        }
}

// ---------------------------------------------------------------------------
extern "C" void kernel_launch(void* const* d_in, const int* in_sizes, int n_in,
                              void* d_out, int out_size, void* d_ws, size_t ws_size,
                              hipStream_t stream) {
    const float* query = (const float*)d_in[0];
    // d_in[1] (key) and d_in[2] (value) are unused by the reference
    const float* w_qkv = (const float*)d_in[3];
    const float* w_out = (const float*)d_in[4];
    float* out = (float*)d_out;

    const int M = kBATCH * kS;             // 4096
    const int nQ = M * kE;                 // 4,194,304
    const int nWqkv = 3 * kE * kE;         // 3,145,728

    // workspace (lifetime-overlapped; tab parked past the 48MB working set):
    //   [0,24M)   qkv_raw (gemm1 out) -> later ctx [0,8M) + w_out_b [8M,10M)
    //   [24,48M)  qd | kd | vt ; query_b/w_qkv_b alias qd/kd pre-rope
    //   [48,48.5M) rope cos/sin table (fp32, 2048x32 float2)
    char* ws = (char*)d_ws;
    __bf16* qkv_raw = (__bf16*)ws;
    __bf16* ctx     = (__bf16*)ws;                       // alias, post-vtrans
    __bf16* w_out_b = (__bf16*)(ws + (size_t)8388608);   // alias, post-vtrans
    __bf16* qd      = (__bf16*)(ws + (size_t)25165824);
    __bf16* kd      = (__bf16*)(ws + (size_t)33554432);
    __bf16* vt      = (__bf16*)(ws + (size_t)41943040);
    float2* tab     = (float2*)(ws + ((size_t)48 << 20));
    __bf16* query_b = qd;      // alias, dead after GEMM1
    __bf16* w_qkv_b = kd;      // alias, dead after GEMM1

    // 1) fp32 -> bf16 for query + w_qkv, plus rope trig table (64 blocks)
    cvt2_kernel<<<7168 + 64, 256, 0, stream>>>(query, query_b, nQ, w_qkv, w_qkv_b, tab);

    // 2) QKV projection (128x128 tile, BK=64)
    gemm_bt_kernel<128, __bf16>
        <<<dim3(3 * kE / 128, M / 128), 256, 0, stream>>>(query_b, w_qkv_b, qkv_raw, M, 3 * kE, kE);

    // 3) RoPE on q,k (table-based, q pre-scaled) + sigma-permuted V transpose
    rope_vtrans_kernel<<<8192 + 1024, 256, 0, stream>>>(qkv_raw, qd, kd, vt, tab);

    // 4) attention (4 waves x 32 q-rows, 1-deep softmax pipeline, K2/V4 rings)
    attn_kernel<<<512, 256, 0, stream>>>(qd, kd, vt, ctx, w_out, w_out_b);

    // 5) output projection (128x64 tile -> 512 blocks, fp32 out)
    gemm_bt_kernel<64, float>
        <<<dim3(kE / 64, M / 128), 256, 0, stream>>>(ctx, w_out_b, out, M, kE, kE);
}